// Round 7
// baseline (335.724 us; speedup 1.0000x reference)
//
#include <hip/hip_runtime.h>
#include <hip/hip_bf16.h>
#include <stdint.h>

#define N_TOK 8192
#define DIN   1024
#define DOUT  1024
#define HID   1024
#define NE    8
#define CAP   0.8f   // 1 - EPS

typedef __attribute__((ext_vector_type(8))) short short8;
typedef __attribute__((ext_vector_type(4))) float floatx4;

__device__ __forceinline__ void async_load16(const void* g, void* l) {
  __builtin_amdgcn_global_load_lds(
      (const __attribute__((address_space(1))) void*)g,
      (__attribute__((address_space(3))) void*)l,
      16, 0, 0);
}

__device__ __forceinline__ unsigned short bf16_bits(float f) {
  return __builtin_bit_cast(unsigned short, __float2bfloat16(f));
}
__device__ __forceinline__ float bits_to_f32(unsigned short b) {
  return __builtin_bit_cast(float, (unsigned int)b << 16);
}

// ---------------------------------------------------------------------------
// Zero-fill d_out — FALLBACK path only (atomic FC2 needs zeroed out).
// ---------------------------------------------------------------------------
__global__ __launch_bounds__(256) void zero_kernel(float4* __restrict__ out4, int n4) {
  const int stride = gridDim.x * 256;
  for (int i = blockIdx.x * 256 + threadIdx.x; i < n4; i += stride)
    out4[i] = (float4){0.f, 0.f, 0.f, 0.f};
}

// ---------------------------------------------------------------------------
// Selector: logits = x @ Wsel + bsel ; softmax ; capped-cumsum sparse weights
// (gather-with-order per torch.gather semantics). Emits x as bf16 + sw.
// NO atomics (round-2 lesson: 65k returning atomics on one line = 155 us).
// ---------------------------------------------------------------------------
__global__ __launch_bounds__(256) void selector_kernel(
    const float* __restrict__ x, const float* __restrict__ Wsel,
    const float* __restrict__ bsel,
    __hip_bfloat16* __restrict__ x_bf, float* __restrict__ sw)
{
  const int lane = threadIdx.x & 63;
  const int wave = threadIdx.x >> 6;
  const int n = blockIdx.x * 4 + wave;
  const float4* xr4 = (const float4*)(x + (size_t)n * DIN);
  ushort4* xb4 = (ushort4*)(x_bf + (size_t)n * DIN);

  float acc[8];
#pragma unroll
  for (int e = 0; e < 8; e++) acc[e] = 0.f;

#pragma unroll
  for (int i = 0; i < 4; i++) {
    const int d4 = lane + i * 64;
    const float4 xv = xr4[d4];
    ushort4 p;
    p.x = bf16_bits(xv.x);
    p.y = bf16_bits(xv.y);
    p.z = bf16_bits(xv.z);
    p.w = bf16_bits(xv.w);
    xb4[d4] = p;
    const float xs[4] = {xv.x, xv.y, xv.z, xv.w};
#pragma unroll
    for (int q = 0; q < 4; q++) {
      const int d = d4 * 4 + q;
      const float4* wr = (const float4*)(Wsel + d * 8);
      const float4 wlo = wr[0], whi = wr[1];
      const float xv1 = xs[q];
      acc[0] += xv1 * wlo.x; acc[1] += xv1 * wlo.y;
      acc[2] += xv1 * wlo.z; acc[3] += xv1 * wlo.w;
      acc[4] += xv1 * whi.x; acc[5] += xv1 * whi.y;
      acc[6] += xv1 * whi.z; acc[7] += xv1 * whi.w;
    }
  }
#pragma unroll
  for (int off = 32; off >= 1; off >>= 1)
#pragma unroll
    for (int e = 0; e < 8; e++) acc[e] += __shfl_xor(acc[e], off);

  if (lane == 0) {
    float w[8];
    float mx = -1e30f;
#pragma unroll
    for (int e = 0; e < 8; e++) { w[e] = acc[e] + bsel[e]; mx = fmaxf(mx, w[e]); }
    float s = 0.f;
#pragma unroll
    for (int e = 0; e < 8; e++) { w[e] = expf(w[e] - mx); s += w[e]; }
    const float inv = 1.f / s;
#pragma unroll
    for (int e = 0; e < 8; e++) w[e] *= inv;

    // stable descending argsort (insertion sort; strict < keeps ties stable)
    float wsrt[8]; int ord[8];
    for (int k = 0; k < 8; k++) {
      const float v = w[k];
      int j = k;
      while (j > 0 && wsrt[j - 1] < v) { wsrt[j] = wsrt[j - 1]; ord[j] = ord[j - 1]; j--; }
      wsrt[j] = v; ord[j] = k;
    }
    // capped cumulative sparse weights (sorted order)
    float cum = 0.f, sws[8];
    for (int k = 0; k < 8; k++) {
      cum += wsrt[k];
      const float capped = fminf(cum, CAP);
      sws[k] = fmaxf(capped - cum + wsrt[k], 0.f);
    }
    // faithful to torch.gather(sparse_weight, 1, index): sw[j] = sws[ord[j]]
    for (int j = 0; j < 8; j++) sw[(size_t)n * 8 + j] = sws[ord[j]];
  }
}

// ---------------------------------------------------------------------------
// Per-expert token compaction with ZERO global atomics. Also records pos:
// pos[tok*8+e] = slot of tok in expert e's list (valid only where sw>0).
// ---------------------------------------------------------------------------
__global__ __launch_bounds__(1024) void compact_kernel(
    const float* __restrict__ sw, int* __restrict__ idx,
    int* __restrict__ pos, int* __restrict__ cnt)
{
  const int e = blockIdx.x;
  const int t = threadIdx.x;
  const int lane = t & 63;
  const int wv = t >> 6;
  __shared__ int wave_base[16];
  __shared__ int chunk_total;
  int base = 0;
#pragma unroll
  for (int c = 0; c < 8; c++) {
    const int tok = c * 1024 + t;
    const bool act = sw[(size_t)tok * 8 + e] > 0.f;
    const unsigned long long m = __ballot(act);
    const int before = __popcll(m & ((1ull << lane) - 1ull));
    if (lane == 0) wave_base[wv] = __popcll(m);
    __syncthreads();
    if (t == 0) {
      int s = 0;
      for (int w = 0; w < 16; w++) { const int v = wave_base[w]; wave_base[w] = s; s += v; }
      chunk_total = s;
    }
    __syncthreads();
    if (act) {
      const int p = base + wave_base[wv] + before;
      idx[e * N_TOK + p] = tok;
      pos[(size_t)tok * 8 + e] = p;
    }
    base += chunk_total;
    __syncthreads();
  }
  if (t == 0) cnt[e] = base;
}

// ---------------------------------------------------------------------------
// W1[e][k][n] fp32 -> W1t[e][n][k] bf16 ; W2[e][h][o] fp32 -> W2t[e][o][h] bf16
// ---------------------------------------------------------------------------
__global__ __launch_bounds__(256) void convert_weights_kernel(
    const float* __restrict__ W1, const float* __restrict__ W2,
    __hip_bfloat16* __restrict__ W1t, __hip_bfloat16* __restrict__ W2t)
{
  __shared__ float tile[32][33];
  const int z = blockIdx.z;
  const float* src = (z & 8) ? W2 : W1;
  __hip_bfloat16* dst = (z & 8) ? W2t : W1t;
  const int e = z & 7;
  src += (size_t)e * 1024 * 1024;
  dst += (size_t)e * 1024 * 1024;
  const int R = blockIdx.y * 32, C = blockIdx.x * 32;
  const int c = threadIdx.x & 31, r0 = threadIdx.x >> 5;
#pragma unroll
  for (int p = 0; p < 4; p++) {
    const int r = r0 + p * 8;
    tile[r][c] = src[(size_t)(R + r) * 1024 + C + c];
  }
  __syncthreads();
#pragma unroll
  for (int p = 0; p < 4; p++) {
    const int r = r0 + p * 8;
    dst[(size_t)(C + r) * 1024 + R + c] = __float2bfloat16(tile[c][r]);
  }
}

// ---------------------------------------------------------------------------
// Compacted per-expert GEMM: 128x128 tile, BK=64, swizzled LDS (0 conflicts,
// verified round 6). 1-D grid id = n-cls + 8*(mslot + 64*e).
// MODE 0 (FC1):        hpool[e] = bf16(relu(A W1t^T + b1)), A = gather(x_bf)
// MODE 1 (FC2 pooled): ypool[e] = bf16(A W2t^T + b2), A = hpool[e]  (no atomics;
//                      round-6 lesson: 12.5M scattered fp32 atomic RMWs bound FC2)
// MODE 2 (FC2 atomic): ws-too-small fallback = round-6 behavior
// ---------------------------------------------------------------------------
template <int MODE>
__global__ __launch_bounds__(256, 3) void moe_gemm(
    const __hip_bfloat16* __restrict__ x_bf,
    __hip_bfloat16* __restrict__ hpool,
    __hip_bfloat16* __restrict__ ypool,
    const __hip_bfloat16* __restrict__ Wt,
    const float* __restrict__ biasAll,
    const float* __restrict__ sw,
    const int* __restrict__ idx, const int* __restrict__ cnt,
    float* __restrict__ out)
{
  const int id = blockIdx.x;
  const int n = id & 7;
  const int q = id >> 3;
  const int mslot = q & 63;
  const int e = q >> 6;

  const int count = cnt[e];
  const int m0 = mslot * 128;
  if (m0 >= count) return;
  const int n0 = n * 128;

  __shared__ __align__(16) __hip_bfloat16 sA[128 * 64];
  __shared__ __align__(16) __hip_bfloat16 sB[128 * 64];
  const int t = threadIdx.x;
  const int lane = t & 63;
  const int wave = t >> 6;
  const int wm = (wave & 1) * 64;
  const int wn = (wave >> 1) * 64;
  const int* idx_e = idx + e * N_TOK;
  const float* bias = biasAll + e * 1024;

  floatx4 acc[4][4];
#pragma unroll
  for (int i = 0; i < 4; i++)
#pragma unroll
    for (int j = 0; j < 4; j++) acc[i][j] = (floatx4){0.f, 0.f, 0.f, 0.f};

  // staging: thread t stages 16 B for rows r0+{0,32,64,96}; swizzled k-chunk
  const int r0 = t >> 3;               // 0..31
  const int c8 = t & 7;                // LDS chunk within row
  const int g8 = ((c8 + r0) & 7) * 8;  // global k-offset ((r0+p*32)&7 == r0&7)
  const __hip_bfloat16* Arow[4];
#pragma unroll
  for (int p = 0; p < 4; p++) {
    if (MODE == 0) {
      const int tok = idx_e[min(m0 + r0 + p * 32, count - 1)];  // clamp tail
      Arow[p] = x_bf + (size_t)tok * 1024;
    } else {
      // tail rows read poison (finite); epilogue discards gm >= count
      Arow[p] = hpool + ((size_t)e * N_TOK + m0 + r0 + p * 32) * 1024;
    }
  }
  const __hip_bfloat16* Brow = Wt + (size_t)e * 1024 * 1024 + (size_t)(n0 + r0) * 1024;
  __hip_bfloat16* lA = &sA[r0 * 64 + c8 * 8];
  __hip_bfloat16* lB = &sB[r0 * 64 + c8 * 8];

  const int rf = lane & 15;
  const int gquad = lane >> 4;

  for (int k0 = 0; k0 < 1024; k0 += 64) {
#pragma unroll
    for (int p = 0; p < 4; p++) {
      async_load16(Arow[p] + k0 + g8, lA + p * 32 * 64);
      async_load16(Brow + (size_t)p * 32 * 1024 + k0 + g8, lB + p * 32 * 64);
    }
    __syncthreads();
#pragma unroll
    for (int kk = 0; kk < 2; kk++) {
      const int gc = gquad + kk * 4;
      short8 aF[4], bF[4];
#pragma unroll
      for (int i = 0; i < 4; i++) {
        const int r = wm + i * 16 + rf;
        aF[i] = *(const short8*)&sA[r * 64 + ((gc - r) & 7) * 8];
      }
#pragma unroll
      for (int j = 0; j < 4; j++) {
        const int r = wn + j * 16 + rf;
        bF[j] = *(const short8*)&sB[r * 64 + ((gc - r) & 7) * 8];
      }
#pragma unroll
      for (int i = 0; i < 4; i++)
#pragma unroll
        for (int j = 0; j < 4; j++)
          acc[i][j] = __builtin_amdgcn_mfma_f32_16x16x32_bf16(aF[i], bF[j], acc[i][j], 0, 0, 0);
    }
    __syncthreads();
  }

  // epilogue: C/D layout col = lane&15, row = (lane>>4)*4 + reg
  const int quad = lane >> 4;
  const int cn = lane & 15;
#pragma unroll
  for (int i = 0; i < 4; i++) {
#pragma unroll
    for (int r = 0; r < 4; r++) {
      const int gm = m0 + wm + i * 16 + quad * 4 + r;
      if (gm >= count) continue;
      int tok = 0; float swv = 0.f;
      if (MODE == 2) {
        tok = idx_e[gm];
        swv = sw[tok * 8 + e];
      }
#pragma unroll
      for (int j = 0; j < 4; j++) {
        const int gn = n0 + wn + j * 16 + cn;
        const float v = acc[i][j][r] + bias[gn];
        if (MODE == 0) {
          hpool[((size_t)e * N_TOK + gm) * 1024 + gn] = __float2bfloat16(fmaxf(v, 0.f));
        } else if (MODE == 1) {
          ypool[((size_t)e * N_TOK + gm) * 1024 + gn] = __float2bfloat16(v);
        } else {
          unsafeAtomicAdd(&out[(size_t)tok * 1024 + gn], swv * v);
        }
      }
    }
  }
}

// ---------------------------------------------------------------------------
// Combine: out[n] = sum_{j: sw[n][j]>0} sw[n][j] * ypool[j][pos[n][j]].
// One wave per token; fully coalesced (lane-contiguous 8B reads / 16B writes).
// Writes every row -> no out zero-fill needed.
// ---------------------------------------------------------------------------
__global__ __launch_bounds__(256) void combine_kernel(
    const float* __restrict__ sw, const int* __restrict__ pos,
    const __hip_bfloat16* __restrict__ ypool, float* __restrict__ out)
{
  const int lane = threadIdx.x & 63;
  const int wave = threadIdx.x >> 6;
  const int n = blockIdx.x * 4 + wave;

  const float4* swr = (const float4*)(sw + (size_t)n * 8);
  const float4 s0 = swr[0], s1 = swr[1];
  const float swl[8] = {s0.x, s0.y, s0.z, s0.w, s1.x, s1.y, s1.z, s1.w};
  const int4* pr = (const int4*)(pos + (size_t)n * 8);
  const int4 p0 = pr[0], p1 = pr[1];
  const int pl[8] = {p0.x, p0.y, p0.z, p0.w, p1.x, p1.y, p1.z, p1.w};

  float acc[16];
#pragma unroll
  for (int i = 0; i < 16; i++) acc[i] = 0.f;

#pragma unroll
  for (int j = 0; j < 8; j++) {
    if (swl[j] > 0.f) {
      const float wj = swl[j];
      const unsigned short* yr =
          (const unsigned short*)(ypool + ((size_t)j * N_TOK + pl[j]) * 1024);
#pragma unroll
      for (int q = 0; q < 4; q++) {
        const ushort4 v = *(const ushort4*)(yr + q * 256 + lane * 4);
        acc[q * 4 + 0] += wj * bits_to_f32(v.x);
        acc[q * 4 + 1] += wj * bits_to_f32(v.y);
        acc[q * 4 + 2] += wj * bits_to_f32(v.z);
        acc[q * 4 + 3] += wj * bits_to_f32(v.w);
      }
    }
  }
#pragma unroll
  for (int q = 0; q < 4; q++) {
    float4 o = {acc[q * 4 + 0], acc[q * 4 + 1], acc[q * 4 + 2], acc[q * 4 + 3]};
    *(float4*)(out + (size_t)n * 1024 + q * 256 + lane * 4) = o;
  }
}

// ---------------------------------------------------------------------------
extern "C" void kernel_launch(void* const* d_in, const int* in_sizes, int n_in,
                              void* d_out, int out_size, void* d_ws, size_t ws_size,
                              hipStream_t stream) {
  const float* x    = (const float*)d_in[0];
  const float* Wsel = (const float*)d_in[1];
  const float* bsel = (const float*)d_in[2];
  const float* W1   = (const float*)d_in[3];
  const float* b1   = (const float*)d_in[4];
  const float* W2   = (const float*)d_in[5];
  const float* b2   = (const float*)d_in[6];
  float* out = (float*)d_out;

  char* ws = (char*)d_ws;
  __hip_bfloat16* x_bf = (__hip_bfloat16*)ws; ws += (size_t)N_TOK * DIN * 2;
  __hip_bfloat16* W1t  = (__hip_bfloat16*)ws; ws += (size_t)NE * DIN * HID * 2;
  __hip_bfloat16* W2t  = (__hip_bfloat16*)ws; ws += (size_t)NE * HID * DOUT * 2;
  float* sw            = (float*)ws;          ws += (size_t)N_TOK * NE * 4;
  int* idx             = (int*)ws;            ws += (size_t)NE * N_TOK * 4;
  int* pos             = (int*)ws;            ws += (size_t)NE * N_TOK * 4;
  int* cnt             = (int*)ws;            ws += 256;
  __hip_bfloat16* hpool = (__hip_bfloat16*)ws; ws += (size_t)NE * N_TOK * HID * 2;
  __hip_bfloat16* ypool = (__hip_bfloat16*)ws;  // NE*N_TOK*DOUT*2 = 134 MB
  const size_t need_pool = (size_t)(ws - (char*)d_ws) + (size_t)NE * N_TOK * DOUT * 2;
  const bool pooled = ws_size >= need_pool;

  selector_kernel<<<N_TOK / 4, 256, 0, stream>>>(x, Wsel, bsel, x_bf, sw);
  compact_kernel<<<NE, 1024, 0, stream>>>(sw, idx, pos, cnt);
  convert_weights_kernel<<<dim3(32, 32, 16), 256, 0, stream>>>(W1, W2, W1t, W2t);

  moe_gemm<0><<<8 * 64 * 8, 256, 0, stream>>>(
      x_bf, hpool, ypool, W1t, b1, sw, idx, cnt, out);
  if (pooled) {
    moe_gemm<1><<<8 * 64 * 8, 256, 0, stream>>>(
        x_bf, hpool, ypool, W2t, b2, sw, idx, cnt, out);
    combine_kernel<<<N_TOK / 4, 256, 0, stream>>>(sw, pos, ypool, out);
  } else {
    zero_kernel<<<1024, 256, 0, stream>>>((float4*)out, N_TOK * DOUT / 4);
    moe_gemm<2><<<8 * 64 * 8, 256, 0, stream>>>(
        x_bf, hpool, ypool, W2t, b2, sw, idx, cnt, out);
  }
}